// Round 21
// baseline (363.518 us; speedup 1.0000x reference)
//
#include <hip/hip_runtime.h>
#include <hip/hip_fp8.h>
#include <stdint.h>

typedef __attribute__((ext_vector_type(2))) __bf16 bf16x2;
typedef __attribute__((ext_vector_type(4))) __bf16 bf16x4;
typedef __attribute__((ext_vector_type(8))) __bf16 bf16x8;
typedef __attribute__((ext_vector_type(4))) float f32x4;

#define DEV __device__ __forceinline__

DEV void g2lds16(const void* g, void* l) {
  __builtin_amdgcn_global_load_lds(
      (const __attribute__((address_space(1))) void*)g,
      (__attribute__((address_space(3))) void*)l, 16, 0, 0);
}
DEV void bar() {
  asm volatile("" ::: "memory");
  __builtin_amdgcn_s_barrier();
  asm volatile("" ::: "memory");
}
DEV void vm4() { asm volatile("s_waitcnt vmcnt(4)" ::: "memory"); }
DEV void vm0() { asm volatile("s_waitcnt vmcnt(0)" ::: "memory"); }

DEV unsigned char to_e4m3(float v) {
  __hip_fp8_e4m3 f8(v);
  return *reinterpret_cast<unsigned char*>(&f8);
}

// ---- f32 -> bf16 vector convert (x) ----
__global__ __launch_bounds__(256) void cvt_f32_bf16(const float* __restrict__ s,
                                                    __bf16* __restrict__ d, int n) {
  int i = (blockIdx.x * 256 + threadIdx.x) * 4;
  if (i >= n) return;
  float4 v = *reinterpret_cast<const float4*>(s + i);
  bf16x4 o;
  o[0] = (__bf16)v.x; o[1] = (__bf16)v.y; o[2] = (__bf16)v.z; o[3] = (__bf16)v.w;
  *reinterpret_cast<bf16x4*>(d + i) = o;
}

// ---- tiled transpose f32[K][N] -> bf16[Npad][K] ----
__global__ __launch_bounds__(256) void transpose_to_bf16(const float* __restrict__ src,
                                                         __bf16* __restrict__ dst,
                                                         int K, int N, int Npad) {
  __shared__ float tile[32][33];
  int n0 = blockIdx.x * 32, k0 = blockIdx.y * 32;
  int tx = threadIdx.x & 31, ty = threadIdx.x >> 5;
#pragma unroll
  for (int j = 0; j < 4; ++j) {
    int k = k0 + ty + j * 8;
    int n = n0 + tx;
    float v = 0.f;
    if (n < N) v = src[(long)k * N + n];
    tile[ty + j * 8][tx] = v;
  }
  __syncthreads();
#pragma unroll
  for (int j = 0; j < 4; ++j) {
    int n = n0 + ty + j * 8;
    int k = k0 + tx;
    if (n < Npad) dst[(long)n * K + k] = (__bf16)tile[tx][ty + j * 8];
  }
}

// ---- tiled transpose f32[K][N] -> fp8 e4m3 [N][K], scaled ----
__global__ __launch_bounds__(256) void transpose_to_fp8(const float* __restrict__ src,
                                                        unsigned char* __restrict__ dst,
                                                        int K, int N, float scale) {
  __shared__ float tile[32][33];
  int n0 = blockIdx.x * 32, k0 = blockIdx.y * 32;
  int tx = threadIdx.x & 31, ty = threadIdx.x >> 5;
#pragma unroll
  for (int j = 0; j < 4; ++j)
    tile[ty + j * 8][tx] = src[(long)(k0 + ty + j * 8) * N + n0 + tx];
  __syncthreads();
#pragma unroll
  for (int j = 0; j < 4; ++j) {
    int n = n0 + ty + j * 8;
    int k = k0 + tx;
    dst[(long)n * K + k] = to_e4m3(tile[tx][ty + j * 8] * scale);
  }
}

// ============================================================================
// GEMM1: 128x128 bf16 MFMA, triple-buffered LDS, depth-2 prefetch, vmcnt(4).
// (round-18 proven config: 103 us, MfmaUtil 31%, conflicts 0)  K=1024 fixed.
// ============================================================================
#define STAGE3(BUF, KC)                                              \
  { g2lds16(A + aoffg0 + (KC), &As[BUF][q0 * 8]);                    \
    g2lds16(A + aoffg1 + (KC), &As[BUF][q1 * 8]);                    \
    g2lds16(Wt + boffg0 + (KC), &Bs[BUF][q0 * 8]);                   \
    g2lds16(Wt + boffg1 + (KC), &Bs[BUF][q1 * 8]); }

#define COMPUTE3(CUR)                                                \
  { bf16x8 af[4], bw[4];                                             \
    _Pragma("unroll") for (int i = 0; i < 4; ++i)                    \
        af[i] = *reinterpret_cast<const bf16x8*>(&As[CUR][aoffl[i]]);\
    _Pragma("unroll") for (int n = 0; n < 4; ++n)                    \
        bw[n] = *reinterpret_cast<const bf16x8*>(&Bs[CUR][boffl[n]]);\
    __builtin_amdgcn_s_setprio(1);                                   \
    _Pragma("unroll") for (int i = 0; i < 4; ++i)                    \
      _Pragma("unroll") for (int n = 0; n < 4; ++n)                  \
          acc[i][n] = __builtin_amdgcn_mfma_f32_16x16x32_bf16(       \
              af[i], bw[n], acc[i][n], 0, 0, 0);                     \
    __builtin_amdgcn_s_setprio(0); }

#define ITER3(CUR, STG, KC) \
  STAGE3(STG, KC); COMPUTE3(CUR); vm4(); bar();

__global__ __launch_bounds__(256, 3) void gemm_p3(const __bf16* __restrict__ A,
                                                  const __bf16* __restrict__ Wt,
                                                  const float* __restrict__ bias,
                                                  __bf16* __restrict__ Cout,
                                                  int Nreal, int ldc, int gx) {
  constexpr int K = 1024;
  __shared__ __bf16 As[3][4096];
  __shared__ __bf16 Bs[3][4096];
  const int tid = threadIdx.x;
  const int lane = tid & 63, wid = tid >> 6;

  const int nwg = gridDim.x;
  const int orig = blockIdx.x;
  const int wg = ((orig & 7) * (nwg >> 3)) + (orig >> 3);
  const int tm = (wg / gx) * 128, tn = (wg % gx) * 128;

  f32x4 acc[4][4] = {};

  const int q0 = tid, q1 = tid + 256;
  const int row0 = ((q0 >> 3) << 1) | ((q0 >> 2) & 1);
  const int c0e = (((q0 & 3) - (q0 >> 3)) & 3) * 8;
  const int row1 = row0 + 64;
  const long aoffg0 = (long)(tm + row0) * K + c0e;
  const long aoffg1 = (long)(tm + row1) * K + c0e;
  const long boffg0 = (long)(tn + row0) * K + c0e;
  const long boffg1 = (long)(tn + row1) * K + c0e;

  const int l15 = lane & 15, cl = lane >> 4;
  int aoffl[4], boffl[4];
#pragma unroll
  for (int mf = 0; mf < 4; ++mf) {
    int row = (wid >> 1) * 64 + mf * 16 + l15;
    aoffl[mf] = (row >> 1) * 64 + (((row & 1) << 2) | ((cl + (row >> 1)) & 3)) * 8;
  }
#pragma unroll
  for (int nf = 0; nf < 4; ++nf) {
    int row = (wid & 1) * 64 + nf * 16 + l15;
    boffl[nf] = (row >> 1) * 64 + (((row & 1) << 2) | ((cl + (row >> 1)) & 3)) * 8;
  }

  STAGE3(0, 0);
  STAGE3(1, 32);
  vm4();
  bar();

#pragma unroll 1
  for (int i = 0; i < 10; ++i) {
    const int kc = (3 * i + 2) << 5;
    ITER3(0, 2, kc);
    ITER3(1, 0, kc + 32);
    ITER3(2, 1, kc + 64);
  }
  COMPUTE3(0); vm0(); bar();
  COMPUTE3(1);

#pragma unroll
  for (int mf = 0; mf < 4; ++mf) {
    const int rg = tm + (wid >> 1) * 64 + mf * 16 + (lane >> 4) * 4;
#pragma unroll
    for (int nf = 0; nf < 4; ++nf) {
      int col = tn + (wid & 1) * 64 + nf * 16 + l15;
      if (col < Nreal) {
        float bv = bias[col];
#pragma unroll
        for (int r = 0; r < 4; ++r)
          Cout[(long)(rg + r) * ldc + col] = (__bf16)(acc[mf][nf][r] + bv);
      }
    }
  }
}

// ============================================================================
// GEMM2: 128x128 FP8 e4m3 MFMA (16x16x32_fp8_fp8), BK=64, triple-buffered,
// depth-2 prefetch, vmcnt(4). Same slot-swizzle algebra as p3 at 16B units
// over 64B rows. A = fp8(s/2), B = fp8(2*mix_w)  =>  A.B = s.w exactly scaled.
// Per iter: 32 MFMA vs same LDS bytes as bf16's 16 -> read-bound ratio halves.
// ============================================================================
#define STAGEF8(BUF, KC)                                             \
  { g2lds16(A + aoffg0 + (KC), &As[BUF][q0 * 16]);                   \
    g2lds16(A + aoffg1 + (KC), &As[BUF][q1 * 16]);                   \
    g2lds16(Wt + boffg0 + (KC), &Bs[BUF][q0 * 16]);                  \
    g2lds16(Wt + boffg1 + (KC), &Bs[BUF][q1 * 16]); }

#define COMPUTEF8(CUR)                                                        \
  { long long af[4][2], bw[4][2];                                             \
    _Pragma("unroll") for (int i = 0; i < 4; ++i)                             \
      _Pragma("unroll") for (int k = 0; k < 2; ++k) {                         \
        af[i][k] = *reinterpret_cast<const long long*>(&As[CUR][aoffl[i][k]]);\
        bw[i][k] = *reinterpret_cast<const long long*>(&Bs[CUR][boffl[i][k]]);\
      }                                                                       \
    __builtin_amdgcn_s_setprio(1);                                            \
    _Pragma("unroll") for (int k = 0; k < 2; ++k)                             \
      _Pragma("unroll") for (int i = 0; i < 4; ++i)                           \
        _Pragma("unroll") for (int n = 0; n < 4; ++n)                         \
            acc[i][n] = __builtin_amdgcn_mfma_f32_16x16x32_fp8_fp8(           \
                af[i][k], bw[n][k], acc[i][n], 0, 0, 0);                      \
    __builtin_amdgcn_s_setprio(0); }

#define ITERF8(CUR, STG, KC) \
  STAGEF8(STG, KC); COMPUTEF8(CUR); vm4(); bar();

__global__ __launch_bounds__(256, 3) void gemm_f8(const unsigned char* __restrict__ A,
                                                  const unsigned char* __restrict__ Wt,
                                                  const float* __restrict__ bias,
                                                  __bf16* __restrict__ Cout,
                                                  int ldc, int gx) {
  constexpr int K = 2048;  // fp8 elements (bytes) per row
  __shared__ unsigned char As[3][8192];  // 128 rows x 64 B
  __shared__ unsigned char Bs[3][8192];
  const int tid = threadIdx.x;
  const int lane = tid & 63, wid = tid >> 6;

  const int nwg = gridDim.x;
  const int orig = blockIdx.x;
  const int wg = ((orig & 7) * (nwg >> 3)) + (orig >> 3);
  const int tm = (wg / gx) * 128, tn = (wg % gx) * 128;

  f32x4 acc[4][4] = {};

  // staging decode: chunk q (16B) -> row=((q>>3)<<1)|((q>>2)&1), global 16B
  // col sc=((q&3)-(q>>3))&3; LDS dest linear slot q (lane-contiguous).
  const int q0 = tid, q1 = tid + 256;
  const int row0 = ((q0 >> 3) << 1) | ((q0 >> 2) & 1);
  const int c0e = (((q0 & 3) - (q0 >> 3)) & 3) * 16;
  const int row1 = row0 + 64;
  const long aoffg0 = (long)(tm + row0) * K + c0e;
  const long aoffg1 = (long)(tm + row1) * K + c0e;
  const long boffg0 = (long)(tn + row0) * K + c0e;
  const long boffg1 = (long)(tn + row1) * K + c0e;

  // per-lane read offsets (bytes): frag (mf, ks): 8B at slot'(row,sc)*16+sub*8,
  // sc = ks*2 + (cl>>1), sub = cl&1, slot' = (row>>1)*8+((row&1)<<2)+((sc+(row>>1))&3)
  const int l15 = lane & 15, cl = lane >> 4;
  int aoffl[4][2], boffl[4][2];
#pragma unroll
  for (int mf = 0; mf < 4; ++mf) {
    int row = (wid >> 1) * 64 + mf * 16 + l15;
#pragma unroll
    for (int ks = 0; ks < 2; ++ks) {
      int sc = ks * 2 + (cl >> 1);
      aoffl[mf][ks] = ((row >> 1) * 8 + ((row & 1) << 2) + ((sc + (row >> 1)) & 3)) * 16 +
                      (cl & 1) * 8;
    }
  }
#pragma unroll
  for (int nf = 0; nf < 4; ++nf) {
    int row = (wid & 1) * 64 + nf * 16 + l15;
#pragma unroll
    for (int ks = 0; ks < 2; ++ks) {
      int sc = ks * 2 + (cl >> 1);
      boffl[nf][ks] = ((row >> 1) * 8 + ((row & 1) << 2) + ((sc + (row >> 1)) & 3)) * 16 +
                      (cl & 1) * 8;
    }
  }

  // prologue: stage tiles 0,1 (BK=64 bytes each)
  STAGEF8(0, 0);
  STAGEF8(1, 64);
  vm4();
  bar();

  // nt = 2048/64 = 32 tiles: 10 triples + 2 tails
#pragma unroll 1
  for (int i = 0; i < 10; ++i) {
    const int kc = (3 * i + 2) << 6;
    ITERF8(0, 2, kc);
    ITERF8(1, 0, kc + 64);
    ITERF8(2, 1, kc + 128);
  }
  COMPUTEF8(0); vm0(); bar();
  COMPUTEF8(1);

  // epilogue: frag D row=(lane>>4)*4+r, col=lane&15 (dtype-independent)
#pragma unroll
  for (int mf = 0; mf < 4; ++mf) {
    const int rg = tm + (wid >> 1) * 64 + mf * 16 + (lane >> 4) * 4;
#pragma unroll
    for (int nf = 0; nf < 4; ++nf) {
      int col = tn + (wid & 1) * 64 + nf * 16 + l15;
      float bv = bias[col];
#pragma unroll
      for (int r = 0; r < 4; ++r)
        Cout[(long)(rg + r) * ldc + col] = (__bf16)(acc[mf][nf][r] + bv);
    }
  }
}

// ---- u = y * sigmoid(in_gate), coalesced via LDS transpose ----
__global__ __launch_bounds__(256) void u_kernel(const __bf16* __restrict__ pre,
                                                float* __restrict__ u) {
  __shared__ float su[64][33];
  const int b = blockIdx.x >> 5;
  const int t0 = (blockIdx.x & 31) * 64;
  const int tid = threadIdx.x;
  {
    const int r = tid >> 2;
    const int j = (tid & 3) * 8;
    const long rowoff = (long)(b * 2048 + t0 + r) * 2112;
    bf16x8 y8 = *reinterpret_cast<const bf16x8*>(pre + rowoff + j);
    bf16x8 g8 = *reinterpret_cast<const bf16x8*>(pre + rowoff + 1056 + j);
#pragma unroll
    for (int k = 0; k < 8; ++k) {
      float y = (float)y8[k];
      float g = (float)g8[k];
      su[r][j + k] = y / (1.f + expf(-g));
    }
  }
  __syncthreads();
  {
    const int m = tid >> 3;
    const int tt = (tid & 7) * 8;
    float4 o0, o1;
    o0.x = su[tt + 0][m]; o0.y = su[tt + 1][m];
    o0.z = su[tt + 2][m]; o0.w = su[tt + 3][m];
    o1.x = su[tt + 4][m]; o1.y = su[tt + 5][m];
    o1.z = su[tt + 6][m]; o1.w = su[tt + 7][m];
    float* up = u + ((long)(b * 32 + m) * 2048 + t0 + tt);
    *reinterpret_cast<float4*>(up) = o0;
    *reinterpret_cast<float4*>(up + 4) = o1;
  }
}

// ---- scan: fp8(s/2) interleaved (re,im) to ws + Re(s) f32 to d_out ----
__global__ __launch_bounds__(64) void scan_kernel(const float* __restrict__ u,
                                                  const float* __restrict__ a,
                                                  const float* __restrict__ bfr,
                                                  unsigned char* __restrict__ s_f8,
                                                  float* __restrict__ s_re) {
  int blk = blockIdx.x;
  int b = blk >> 4, mp = blk & 15;
  int lane = threadIdx.x;
  int mh = lane >> 5, c = lane & 31;
  int m = mp * 2 + mh;
  const float* ub = u + (long)(b * 32 + m) * 2048;
  float decay = expf(-fabsf(a[m]));
  float gr = decay * cosf(bfr[c]);
  float gi = decay * sinf(bfr[c]);
  float sr = 0.f, si = 0.f;
  long base = (long)b * 2048 * 1024 + m * 32 + c;
  for (int t = 0; t < 2048; ++t) {
    float uv = ub[t];
    float nr = fmaf(gr, sr, fmaf(-gi, si, uv));
    float ni_ = fmaf(gr, si, gi * sr);
    sr = nr; si = ni_;
    long ci = base + (long)t * 1024;
    uchar2 p;
    p.x = to_e4m3(sr * 0.5f);
    p.y = to_e4m3(si * 0.5f);
    *reinterpret_cast<uchar2*>(s_f8 + 2 * ci) = p;
    s_re[ci] = sr;
  }
}

// ---- layernorm + gated mix: z bf16 in -> f32 out ----
__global__ __launch_bounds__(256) void ln_gate_kernel(const __bf16* __restrict__ zb,
                                                      float* __restrict__ out,
                                                      const __bf16* __restrict__ pre) {
  __shared__ float rs[4], rss[4];
  long row = blockIdx.x;
  const __bf16* zp = zb + row * 1024;
  int tid = threadIdx.x;
  bf16x4 zv4 = *reinterpret_cast<const bf16x4*>(zp + tid * 4);
  float v0 = (float)zv4[0], v1 = (float)zv4[1], v2 = (float)zv4[2], v3 = (float)zv4[3];
  float s = v0 + v1 + v2 + v3;
  float ss = v0 * v0 + v1 * v1 + v2 * v2 + v3 * v3;
#pragma unroll
  for (int o = 32; o > 0; o >>= 1) {
    s += __shfl_down(s, o, 64);
    ss += __shfl_down(ss, o, 64);
  }
  if ((tid & 63) == 0) { rs[tid >> 6] = s; rss[tid >> 6] = ss; }
  __syncthreads();
  s = rs[0] + rs[1] + rs[2] + rs[3];
  ss = rss[0] + rss[1] + rss[2] + rss[3];
  float mean = s * (1.f / 1024.f);
  float var = ss * (1.f / 1024.f) - mean * mean;
  float rstd = rsqrtf(var + 1e-5f);
  const __bf16* pr = pre + row * 2112;
  bf16x4 th = *reinterpret_cast<const bf16x4*>(pr + 32 + tid * 4);
  bf16x4 og = *reinterpret_cast<const bf16x4*>(pr + 1088 + tid * 4);
  float4 o; float g;
  g = 1.f / (1.f + expf(-(float)og[0])); o.x = (v0 - mean) * rstd * g + (float)th[0] * (1.f - g);
  g = 1.f / (1.f + expf(-(float)og[1])); o.y = (v1 - mean) * rstd * g + (float)th[1] * (1.f - g);
  g = 1.f / (1.f + expf(-(float)og[2])); o.z = (v2 - mean) * rstd * g + (float)th[2] * (1.f - g);
  g = 1.f / (1.f + expf(-(float)og[3])); o.w = (v3 - mean) * rstd * g + (float)th[3] * (1.f - g);
  *reinterpret_cast<float4*>(out + row * 1024 + tid * 4) = o;
}

extern "C" void kernel_launch(void* const* d_in, const int* in_sizes, int n_in,
                              void* d_out, int out_size, void* d_ws, size_t ws_size,
                              hipStream_t stream) {
  const float* x = (const float*)d_in[0];
  const float* pre_w = (const float*)d_in[1];
  const float* pre_b = (const float*)d_in[2];
  const float* mix_w = (const float*)d_in[3];
  const float* mix_b = (const float*)d_in[4];
  const float* a = (const float*)d_in[5];
  const float* bfr = (const float*)d_in[6];

  // ws (176,685,056 B; ws_size >= 180,617,216 proven by round-5 guard):
  char* ws = (char*)d_ws;
  __bf16* buf0  = (__bf16*)(ws + 0);           // 67,108,864 B (x_bf -> s_f8)
  __bf16* wtbuf = (__bf16*)(ws + 67108864);    //  4,718,592 B (preWT, then mixWT_f8)
  __bf16* pre   = (__bf16*)(ws + 71827456);    // 69,206,016 B [16384][2112]
  float*  u     = (float*)(ws + 141033472);    //  2,097,152 B
  __bf16* z_bf  = (__bf16*)(ws + 143130624);   // 33,554,432 B [16384][1024]
  const size_t WS_NEEDED = 176685056ull;
  if (ws_size < WS_NEEDED) return;

  __bf16* x_bf = buf0;                         // GEMM1 A (dead after GEMM1)
  unsigned char* s_f8 = (unsigned char*)buf0;  // scan output / GEMM2 A
  unsigned char* mixWT_f8 = (unsigned char*)wtbuf;  // after GEMM1

  float* out0 = (float*)d_out;                 // f32 [16384][1024]
  float* s_re = out0 + 16777216;               // f32 Re(s)

  cvt_f32_bf16<<<16384, 256, 0, stream>>>(x, x_bf, 16777216);
  transpose_to_bf16<<<dim3(68, 32), 256, 0, stream>>>(pre_w, wtbuf, 1024, 2112, 2176);
  gemm_p3<<<2176, 256, 0, stream>>>(x_bf, wtbuf, pre_b, pre, 2112, 2112, 17);
  u_kernel<<<256, 256, 0, stream>>>(pre, u);
  transpose_to_fp8<<<dim3(32, 64), 256, 0, stream>>>(mix_w, mixWT_f8, 2048, 1024, 2.0f);
  scan_kernel<<<128, 64, 0, stream>>>(u, a, bfr, s_f8, s_re);  // overwrites x_bf
  gemm_f8<<<1024, 256, 0, stream>>>(s_f8, mixWT_f8, mix_b, z_bf, 1024, 8);
  ln_gate_kernel<<<16384, 256, 0, stream>>>(z_bf, out0, pre);
}